// Round 19
// baseline (4302.488 us; speedup 1.0000x reference)
//
#include <hip/hip_runtime.h>
#include <math.h>

#define NB    4
#define NPER  8192
#define MPER  4096
#define NTOT  32768
#define MTOT  16384
#define COUT  128

// d_out layout (floats): new_x [16384*128] | new_pos [16384*3] | new_batch [16384]
#define NEWPOS_OFF 2097152
#define NEWB_OFF   2146304

// workspace layout (bytes); ~17 MB
#define WS_H     0u           // 32768*128*4 = 16777216
#define WS_SQP   16777216u    // 32768*4
#define WS_SAMP  16908288u    // 16384*4
#define WS_PART  16973824u    // 64*128*4
#define WS_PART2 17006592u    // 64*128*4
#define WS_STAT  17039360u    // 256*4

// ---------------- sq_p + new_batch ----------------
// XLA:CPU fast-math emission of sum(p*p, -1): fma(z,z, fma(x,x, y*y)).
__global__ void misc_kernel(const float* __restrict__ pos, float* __restrict__ sqp,
                            float* __restrict__ out) {
  int g = blockIdx.x * 1024 + threadIdx.x;
  if (g < NTOT) {
    float x = pos[g * 3 + 0], y = pos[g * 3 + 1], z = pos[g * 3 + 2];
    sqp[g] = fmaf(z, z, fmaf(x, x, __fmul_rn(y, y)));
  }
  if (g < MTOT) out[NEWB_OFF + g] = (float)(g >> 12);
}

// ---------------- h_pre = x @ W  (+b) ----------------
__global__ __launch_bounds__(256) void matmul_kernel(const float* __restrict__ x,
                                                     const float* __restrict__ W,
                                                     const float* __restrict__ bias,
                                                     float* __restrict__ h) {
  __shared__ float xs[16][64];
  const int tid = threadIdx.x;
  const int rowbase = blockIdx.x * 16;
  for (int i = tid; i < 16 * 64; i += 256) xs[i >> 6][i & 63] = x[rowbase * 64 + i];
  __syncthreads();
  const int col = tid & 127;
  const int rs = (tid >> 7) * 8;
  float acc[8] = {0.f, 0.f, 0.f, 0.f, 0.f, 0.f, 0.f, 0.f};
  for (int k = 0; k < 64; ++k) {
    float wv = W[k * 128 + col];
#pragma unroll
    for (int r = 0; r < 8; ++r) acc[r] = fmaf(xs[rs + r][k], wv, acc[r]);
  }
  float bb = bias[col];
#pragma unroll
  for (int r = 0; r < 8; ++r) h[(rowbase + rs + r) * 128 + col] = acc[r] + bb;
}

// ---------------- BN partial sums (deterministic tree) ----------------
__global__ __launch_bounds__(256) void stats_kernel(const float* __restrict__ h,
                                                    float* __restrict__ part,
                                                    float* __restrict__ part2) {
  const int tid = threadIdx.x;
  const int col = tid & 127;
  const int half = tid >> 7;
  const int r0 = blockIdx.x * 512;
  float s = 0.f, s2 = 0.f;
  for (int r = r0 + half; r < r0 + 512; r += 2) {
    float v = h[r * 128 + col];
    s += v;
    s2 = fmaf(v, v, s2);
  }
  __shared__ float ps[2][128], ps2[2][128];
  ps[half][col] = s;
  ps2[half][col] = s2;
  __syncthreads();
  if (half == 0) {
    part[blockIdx.x * 128 + col] = ps[0][col] + ps[1][col];
    part2[blockIdx.x * 128 + col] = ps2[0][col] + ps2[1][col];
  }
}

__global__ void finalize_kernel(const float* __restrict__ part,
                                const float* __restrict__ part2,
                                float* __restrict__ stat) {
  int col = threadIdx.x;  // 128 threads
  float s = 0.f, s2 = 0.f;
  for (int i = 0; i < 64; ++i) {
    s += part[i * 128 + col];
    s2 += part2[i * 128 + col];
  }
  float mean = s / 32768.0f;
  float var = s2 / 32768.0f - mean * mean;
  float invstd = 1.0f / sqrtf(var + 1e-5f);
  stat[col] = mean;
  stat[128 + col] = invstd;
}

// ---------------- BN apply + exact GELU (in place on h) ----------------
__global__ __launch_bounds__(256) void bngelu_kernel(float* __restrict__ h,
                                                     const float* __restrict__ stat,
                                                     const float* __restrict__ gamma,
                                                     const float* __restrict__ beta) {
  int base = blockIdx.x * 2048 + threadIdx.x;
#pragma unroll
  for (int t = 0; t < 8; ++t) {
    int g = base + t * 256;
    int col = g & 127;
    float v = h[g];
    float z = (v - stat[col]) * stat[128 + col];
    z = z * gamma[col] + beta[col];
    float ge = 0.5f * z * (1.0f + erff(z * 0.70710678118654752440f));
    h[g] = ge;
  }
}

// ---------------- deterministic FPS, one block per cloud ----------------
// r18 (resident 16-pt register cache, 512 thr, wpe(2,2), two-phase DPP
// selection) + SINGLE-BARRIER collapse: the index match needs only the
// WAVE max (readlane 63 -> SGPR after the DPP fmax reduce), so each wave
// computes its own (max, min-matching-idx) pair and publishes ONE packed
// u64 key (bits(m)<<32 | ~idx -- the r5-proven ordering: max dist, tie ->
// min idx). One barrier, one slot read per step (parity double-buffered,
// r6/r12-validated: step s+2's writes are after barrier s+1 > step-s reads).
#define UMINU(a, b) (((a) < (b)) ? (a) : (b))
#define DPP_FMAX(m, CTRL)                                                       \
  {                                                                             \
    int t_ = __builtin_amdgcn_update_dpp(__float_as_int(m), __float_as_int(m),  \
                                         (CTRL), 0xf, 0xf, false);              \
    m = fmaxf(m, __int_as_float(t_));                                           \
  }
#define DPP_UMIN(c, CTRL)                                                       \
  {                                                                             \
    unsigned int t_ = (unsigned int)__builtin_amdgcn_update_dpp(                \
        (int)(c), (int)(c), (CTRL), 0xf, 0xf, false);                           \
    c = UMINU(c, t_);                                                           \
  }
#define FPS_DECL(i) float px##i, py##i, pz##i, dd##i;
#define FPS_LOAD(i)                     \
  {                                     \
    const int n = tid + (i) * 512;      \
    px##i = p[n * 3 + 0];               \
    py##i = p[n * 3 + 1];               \
    pz##i = p[n * 3 + 2];               \
    dd##i = INFINITY;                   \
    lpxy[n] = make_float2(px##i, py##i);\
    lpz[n] = pz##i;                     \
  }
#define FPS_PIN(i) \
  asm volatile("" : "+v"(px##i), "+v"(py##i), "+v"(pz##i));
#define FPS_DIST(i)                                                             \
  {                                                                             \
    float dx = __fsub_rn(px##i, lx), dy = __fsub_rn(py##i, ly),                 \
          dz = __fsub_rn(pz##i, lz);                                            \
    float d = fmaf(dz, dz, fmaf(dx, dx, __fmul_rn(dy, dy)));                    \
    float nd = fminf(dd##i, d);                                                 \
    dd##i = nd;                                                                 \
    m = fmaxf(m, nd);                                                           \
  }
#define FPS_MATCH(i)                                                            \
  ci = (dd##i == sm) ? (unsigned int)(tid + (i) * 512) : ci;
#define KSEL(a, b) { bool t_ = (b) > (a); a = t_ ? (b) : (a); }

__global__ __launch_bounds__(512)
__attribute__((amdgpu_waves_per_eu(2, 2)))
void fps_kernel(const float* __restrict__ pos,
                int* __restrict__ samp,
                float* __restrict__ out) {
  const int b = blockIdx.x;
  const int tid = threadIdx.x;
  const int wv = tid >> 6;  // wave 0..7
  const float* p = pos + b * NPER * 3;
  __shared__ float2 lpxy[NPER];                   // 64 KB (winner lookup only)
  __shared__ float lpz[NPER];                     // 32 KB
  __shared__ __align__(16) unsigned long long ckey[2][8];
  FPS_DECL(0) FPS_DECL(1) FPS_DECL(2) FPS_DECL(3)
  FPS_DECL(4) FPS_DECL(5) FPS_DECL(6) FPS_DECL(7)
  FPS_DECL(8) FPS_DECL(9) FPS_DECL(10) FPS_DECL(11)
  FPS_DECL(12) FPS_DECL(13) FPS_DECL(14) FPS_DECL(15)
  FPS_LOAD(0) FPS_LOAD(1) FPS_LOAD(2) FPS_LOAD(3)
  FPS_LOAD(4) FPS_LOAD(5) FPS_LOAD(6) FPS_LOAD(7)
  FPS_LOAD(8) FPS_LOAD(9) FPS_LOAD(10) FPS_LOAD(11)
  FPS_LOAD(12) FPS_LOAD(13) FPS_LOAD(14) FPS_LOAD(15)
  FPS_PIN(0) FPS_PIN(1) FPS_PIN(2) FPS_PIN(3)
  FPS_PIN(4) FPS_PIN(5) FPS_PIN(6) FPS_PIN(7)
  FPS_PIN(8) FPS_PIN(9) FPS_PIN(10) FPS_PIN(11)
  FPS_PIN(12) FPS_PIN(13) FPS_PIN(14) FPS_PIN(15)
  float lx = p[0], ly = p[1], lz = p[2];
  if (tid == 0) {
    samp[b * MPER] = 0;
    out[NEWPOS_OFF + (b * MPER) * 3 + 0] = lx;
    out[NEWPOS_OFF + (b * MPER) * 3 + 1] = ly;
    out[NEWPOS_OFF + (b * MPER) * 3 + 2] = lz;
  }
  __syncthreads();
  for (int s = 1; s < MPER; ++s) {
    const int pr = s & 1;
    // ---- dist update + wave max ----
    float m = 0.0f;
    FPS_DIST(0) FPS_DIST(1) FPS_DIST(2) FPS_DIST(3)
    FPS_DIST(4) FPS_DIST(5) FPS_DIST(6) FPS_DIST(7)
    FPS_DIST(8) FPS_DIST(9) FPS_DIST(10) FPS_DIST(11)
    FPS_DIST(12) FPS_DIST(13) FPS_DIST(14) FPS_DIST(15)
    DPP_FMAX(m, 0x111)  // row_shr:1
    DPP_FMAX(m, 0x112)  // row_shr:2
    DPP_FMAX(m, 0x114)  // row_shr:4
    DPP_FMAX(m, 0x118)  // row_shr:8
    DPP_FMAX(m, 0x142)  // row_bcast:15
    DPP_FMAX(m, 0x143)  // row_bcast:31 -> lane 63 has wave max
    // broadcast wave max to all lanes (SGPR, uniform per wave)
    const float sm = __uint_as_float(
        (unsigned int)__builtin_amdgcn_readlane(__float_as_int(m), 63));
    // ---- wave-local min index matching the wave max ----
    unsigned int ci = 0xFFFFFFFFu;
    FPS_MATCH(15) FPS_MATCH(14) FPS_MATCH(13) FPS_MATCH(12)
    FPS_MATCH(11) FPS_MATCH(10) FPS_MATCH(9) FPS_MATCH(8)
    FPS_MATCH(7) FPS_MATCH(6) FPS_MATCH(5) FPS_MATCH(4)
    FPS_MATCH(3) FPS_MATCH(2) FPS_MATCH(1) FPS_MATCH(0)  // descending: i=0 wins
    DPP_UMIN(ci, 0x111)
    DPP_UMIN(ci, 0x112)
    DPP_UMIN(ci, 0x114)
    DPP_UMIN(ci, 0x118)
    DPP_UMIN(ci, 0x142)
    DPP_UMIN(ci, 0x143)     // lane 63 has wave min matching idx
    if ((tid & 63) == 63)
      ckey[pr][wv] = ((unsigned long long)__float_as_uint(sm) << 32) |
                     (unsigned int)(~ci);
    __syncthreads();
    // ---- global reduce of 8 packed keys (broadcast reads, u64 max) ----
    const ulonglong2* cp = (const ulonglong2*)ckey[pr];
    ulonglong2 c0 = cp[0], c1 = cp[1], c2 = cp[2], c3 = cp[3];
    unsigned long long k0 = c0.x; KSEL(k0, c0.y)
    unsigned long long k1 = c1.x; KSEL(k1, c1.y)
    unsigned long long k2 = c2.x; KSEL(k2, c2.y)
    unsigned long long k3 = c3.x; KSEL(k3, c3.y)
    KSEL(k0, k1) KSEL(k2, k3) KSEL(k0, k2)
    const int widx = (int)(~(unsigned int)k0);
    // winner xyz: same-address broadcast LDS reads
    float2 wxy = lpxy[widx];
    float wz = lpz[widx];
    lx = wxy.x; ly = wxy.y; lz = wz;
    if (tid == 0) {
      samp[b * MPER + s] = widx;
      out[NEWPOS_OFF + (b * MPER + s) * 3 + 0] = lx;
      out[NEWPOS_OFF + (b * MPER + s) * 3 + 1] = ly;
      out[NEWPOS_OFF + (b * MPER + s) * 3 + 2] = lz;
    }
    // parity double-buffer: step s+1 writes ckey[pr^1]; step s+2's rewrite
    // of ckey[pr] is ordered after barrier s+1, which follows all step-s reads.
  }
}

// ---------------- kNN: Eigen-style ascending fma dot, expand-formula d2 ----------------
__global__ __launch_bounds__(256) void knn_kernel(const float* __restrict__ pos,
                                                  const float* __restrict__ sqp,
                                                  const int* __restrict__ samp,
                                                  const float* __restrict__ h,
                                                  float* __restrict__ out) {
  const int q = blockIdx.x;
  const int b = q >> 12;
  const int tid = threadIdx.x;
  const int gbase = b * NPER;
  __shared__ float dist[NPER];  // 32 KB
  __shared__ unsigned long long slot[2];
  __shared__ int nbr[16];
  const int sidx = samp[q];
  const float qx = pos[(gbase + sidx) * 3 + 0];
  const float qy = pos[(gbase + sidx) * 3 + 1];
  const float qz = pos[(gbase + sidx) * 3 + 2];
  const float sqq = sqp[gbase + sidx];
  if (tid == 0) {
    slot[0] = ~0ull;
    slot[1] = ~0ull;
  }
  unsigned long long lkey = ~0ull;
  for (int i = 0; i < 32; ++i) {
    int n = tid + i * 256;
    int g = gbase + n;
    // Eigen gebp: fma(q2,p2, fma(q1,p1, rn(q0*p0)))
    float dot = fmaf(qz, pos[g * 3 + 2],
                     fmaf(qy, pos[g * 3 + 1], __fmul_rn(qx, pos[g * 3 + 0])));
    // (sq_q + sq_p) - 2*dot, each op rounded
    float d2 = __fsub_rn(__fadd_rn(sqq, sqp[g]), __fmul_rn(2.0f, dot));
    dist[n] = d2;
    unsigned int ub = __float_as_uint(d2);
    ub = (ub & 0x80000000u) ? ~ub : (ub | 0x80000000u);  // monotone float->uint
    unsigned long long key = ((unsigned long long)ub << 32) | (unsigned int)n;
    lkey = (key < lkey) ? key : lkey;
  }
  __syncthreads();
  for (int r = 0; r < 16; ++r) {
    unsigned long long wk = lkey;
#pragma unroll
    for (int off = 1; off < 64; off <<= 1) {
      unsigned long long o = __shfl_xor(wk, off, 64);
      wk = (o < wk) ? o : wk;
    }
    if ((tid & 63) == 0) atomicMin(&slot[r & 1], wk);
    __syncthreads();
    unsigned long long w = slot[r & 1];
    int n = (int)(unsigned int)(w & 0xFFFFFFFFull);
    if (tid == 0) {
      nbr[r] = n;
      slot[(r & 1) ^ 1] = ~0ull;
    }
    if (tid == (n & 255)) {  // owner removes it and refreshes its local min
      dist[n] = INFINITY;
      lkey = ~0ull;
      for (int i = 0; i < 32; ++i) {
        int nn = tid + i * 256;
        unsigned int ub = __float_as_uint(dist[nn]);
        ub = (ub & 0x80000000u) ? ~ub : (ub | 0x80000000u);
        unsigned long long kk = ((unsigned long long)ub << 32) | (unsigned int)nn;
        lkey = (kk < lkey) ? kk : lkey;
      }
    }
    __syncthreads();
  }
  if (tid < COUT) {
    float mx = -INFINITY;
#pragma unroll
    for (int r = 0; r < 16; ++r) mx = fmaxf(mx, h[(gbase + nbr[r]) * 128 + tid]);
    out[q * 128 + tid] = mx;
  }
}

extern "C" void kernel_launch(void* const* d_in, const int* in_sizes, int n_in,
                              void* d_out, int out_size, void* d_ws, size_t ws_size,
                              hipStream_t stream) {
  (void)in_sizes; (void)n_in; (void)out_size; (void)ws_size;
  const float* x     = (const float*)d_in[0];
  const float* pos   = (const float*)d_in[1];
  const float* W     = (const float*)d_in[3];
  const float* bias  = (const float*)d_in[4];
  const float* gamma = (const float*)d_in[5];
  const float* beta  = (const float*)d_in[6];
  float* out = (float*)d_out;
  char* ws = (char*)d_ws;
  float* h     = (float*)(ws + WS_H);
  float* sqp   = (float*)(ws + WS_SQP);
  int*   samp  = (int*)(ws + WS_SAMP);
  float* part  = (float*)(ws + WS_PART);
  float* part2 = (float*)(ws + WS_PART2);
  float* stat  = (float*)(ws + WS_STAT);

  misc_kernel<<<dim3(32), dim3(1024), 0, stream>>>(pos, sqp, out);
  matmul_kernel<<<dim3(2048), dim3(256), 0, stream>>>(x, W, bias, h);
  stats_kernel<<<dim3(64), dim3(256), 0, stream>>>(h, part, part2);
  finalize_kernel<<<dim3(1), dim3(128), 0, stream>>>(part, part2, stat);
  bngelu_kernel<<<dim3(2048), dim3(256), 0, stream>>>(h, stat, gamma, beta);
  fps_kernel<<<dim3(NB), dim3(512), 0, stream>>>(pos, samp, out);
  knn_kernel<<<dim3(MTOT), dim3(256), 0, stream>>>(pos, sqp, samp, h, out);
}

// Round 20
// 3695.239 us; speedup vs baseline: 1.1643x; 1.1643x over previous
//
#include <hip/hip_runtime.h>
#include <math.h>

#define NB    4
#define NPER  8192
#define MPER  4096
#define NTOT  32768
#define MTOT  16384
#define COUT  128

// d_out layout (floats): new_x [16384*128] | new_pos [16384*3] | new_batch [16384]
#define NEWPOS_OFF 2097152
#define NEWB_OFF   2146304

// workspace layout (bytes); ~17 MB
#define WS_H     0u           // 32768*128*4 = 16777216
#define WS_SQP   16777216u    // 32768*4
#define WS_SAMP  16908288u    // 16384*4
#define WS_PART  16973824u    // 64*128*4
#define WS_PART2 17006592u    // 64*128*4
#define WS_STAT  17039360u    // 256*4

// ---------------- sq_p + new_batch ----------------
// XLA:CPU fast-math emission of sum(p*p, -1): fma(z,z, fma(x,x, y*y)).
__global__ void misc_kernel(const float* __restrict__ pos, float* __restrict__ sqp,
                            float* __restrict__ out) {
  int g = blockIdx.x * 1024 + threadIdx.x;
  if (g < NTOT) {
    float x = pos[g * 3 + 0], y = pos[g * 3 + 1], z = pos[g * 3 + 2];
    sqp[g] = fmaf(z, z, fmaf(x, x, __fmul_rn(y, y)));
  }
  if (g < MTOT) out[NEWB_OFF + g] = (float)(g >> 12);
}

// ---------------- h_pre = x @ W  (+b) ----------------
__global__ __launch_bounds__(256) void matmul_kernel(const float* __restrict__ x,
                                                     const float* __restrict__ W,
                                                     const float* __restrict__ bias,
                                                     float* __restrict__ h) {
  __shared__ float xs[16][64];
  const int tid = threadIdx.x;
  const int rowbase = blockIdx.x * 16;
  for (int i = tid; i < 16 * 64; i += 256) xs[i >> 6][i & 63] = x[rowbase * 64 + i];
  __syncthreads();
  const int col = tid & 127;
  const int rs = (tid >> 7) * 8;
  float acc[8] = {0.f, 0.f, 0.f, 0.f, 0.f, 0.f, 0.f, 0.f};
  for (int k = 0; k < 64; ++k) {
    float wv = W[k * 128 + col];
#pragma unroll
    for (int r = 0; r < 8; ++r) acc[r] = fmaf(xs[rs + r][k], wv, acc[r]);
  }
  float bb = bias[col];
#pragma unroll
  for (int r = 0; r < 8; ++r) h[(rowbase + rs + r) * 128 + col] = acc[r] + bb;
}

// ---------------- BN partial sums (deterministic tree) ----------------
__global__ __launch_bounds__(256) void stats_kernel(const float* __restrict__ h,
                                                    float* __restrict__ part,
                                                    float* __restrict__ part2) {
  const int tid = threadIdx.x;
  const int col = tid & 127;
  const int half = tid >> 7;
  const int r0 = blockIdx.x * 512;
  float s = 0.f, s2 = 0.f;
  for (int r = r0 + half; r < r0 + 512; r += 2) {
    float v = h[r * 128 + col];
    s += v;
    s2 = fmaf(v, v, s2);
  }
  __shared__ float ps[2][128], ps2[2][128];
  ps[half][col] = s;
  ps2[half][col] = s2;
  __syncthreads();
  if (half == 0) {
    part[blockIdx.x * 128 + col] = ps[0][col] + ps[1][col];
    part2[blockIdx.x * 128 + col] = ps2[0][col] + ps2[1][col];
  }
}

__global__ void finalize_kernel(const float* __restrict__ part,
                                const float* __restrict__ part2,
                                float* __restrict__ stat) {
  int col = threadIdx.x;  // 128 threads
  float s = 0.f, s2 = 0.f;
  for (int i = 0; i < 64; ++i) {
    s += part[i * 128 + col];
    s2 += part2[i * 128 + col];
  }
  float mean = s / 32768.0f;
  float var = s2 / 32768.0f - mean * mean;
  float invstd = 1.0f / sqrtf(var + 1e-5f);
  stat[col] = mean;
  stat[128 + col] = invstd;
}

// ---------------- BN apply + exact GELU (in place on h) ----------------
__global__ __launch_bounds__(256) void bngelu_kernel(float* __restrict__ h,
                                                     const float* __restrict__ stat,
                                                     const float* __restrict__ gamma,
                                                     const float* __restrict__ beta) {
  int base = blockIdx.x * 2048 + threadIdx.x;
#pragma unroll
  for (int t = 0; t < 8; ++t) {
    int g = base + t * 256;
    int col = g & 127;
    float v = h[g];
    float z = (v - stat[col]) * stat[128 + col];
    z = z * gamma[col] + beta[col];
    float ge = 0.5f * z * (1.0f + erff(z * 0.70710678118654752440f));
    h[g] = ge;
  }
}

// ---------------- deterministic FPS, one block per cloud ----------------
// EXACT r18 kernel (proven 3245 us, VGPR=88 resident): 512 thr x 16 pts in
// named scalars + pins + waves_per_eu(2,2); two-phase 32-bit DPP selection
// ((A) D = max nd, (B) widx = min{idx : dd == D}); distinct per-wave slots,
// zero atomics, two barriers. r19's single-barrier collapse REGRESSED
// (readlane+double-DPP chain > barrier cost) -- do not restructure.
#define UMAXU(a, b) (((a) > (b)) ? (a) : (b))
#define UMINU(a, b) (((a) < (b)) ? (a) : (b))
#define DPP_FMAX(m, CTRL)                                                       \
  {                                                                             \
    int t_ = __builtin_amdgcn_update_dpp(__float_as_int(m), __float_as_int(m),  \
                                         (CTRL), 0xf, 0xf, false);              \
    m = fmaxf(m, __int_as_float(t_));                                           \
  }
#define DPP_UMIN(c, CTRL)                                                       \
  {                                                                             \
    unsigned int t_ = (unsigned int)__builtin_amdgcn_update_dpp(                \
        (int)(c), (int)(c), (CTRL), 0xf, 0xf, false);                           \
    c = UMINU(c, t_);                                                           \
  }
#define FPS_DECL(i) float px##i, py##i, pz##i, dd##i;
#define FPS_LOAD(i)                     \
  {                                     \
    const int n = tid + (i) * 512;      \
    px##i = p[n * 3 + 0];               \
    py##i = p[n * 3 + 1];               \
    pz##i = p[n * 3 + 2];               \
    dd##i = INFINITY;                   \
    lpxy[n] = make_float2(px##i, py##i);\
    lpz[n] = pz##i;                     \
  }
#define FPS_PIN(i) \
  asm volatile("" : "+v"(px##i), "+v"(py##i), "+v"(pz##i));
#define FPS_DIST(i)                                                             \
  {                                                                             \
    float dx = __fsub_rn(px##i, lx), dy = __fsub_rn(py##i, ly),                 \
          dz = __fsub_rn(pz##i, lz);                                            \
    float d = fmaf(dz, dz, fmaf(dx, dx, __fmul_rn(dy, dy)));                    \
    float nd = fminf(dd##i, d);                                                 \
    dd##i = nd;                                                                 \
    m = fmaxf(m, nd);                                                           \
  }
#define FPS_MATCH(i)                                                            \
  ci = (dd##i == D) ? (unsigned int)(tid + (i) * 512) : ci;

__global__ __launch_bounds__(512)
__attribute__((amdgpu_waves_per_eu(2, 2)))
void fps_kernel(const float* __restrict__ pos,
                int* __restrict__ samp,
                float* __restrict__ out) {
  const int b = blockIdx.x;
  const int tid = threadIdx.x;
  const int wv = tid >> 6;  // wave 0..7
  const float* p = pos + b * NPER * 3;
  __shared__ float2 lpxy[NPER];                   // 64 KB (winner lookup only)
  __shared__ float lpz[NPER];                     // 32 KB
  __shared__ __align__(16) unsigned int slotD[8];
  __shared__ __align__(16) unsigned int slotI[8];
  FPS_DECL(0) FPS_DECL(1) FPS_DECL(2) FPS_DECL(3)
  FPS_DECL(4) FPS_DECL(5) FPS_DECL(6) FPS_DECL(7)
  FPS_DECL(8) FPS_DECL(9) FPS_DECL(10) FPS_DECL(11)
  FPS_DECL(12) FPS_DECL(13) FPS_DECL(14) FPS_DECL(15)
  FPS_LOAD(0) FPS_LOAD(1) FPS_LOAD(2) FPS_LOAD(3)
  FPS_LOAD(4) FPS_LOAD(5) FPS_LOAD(6) FPS_LOAD(7)
  FPS_LOAD(8) FPS_LOAD(9) FPS_LOAD(10) FPS_LOAD(11)
  FPS_LOAD(12) FPS_LOAD(13) FPS_LOAD(14) FPS_LOAD(15)
  FPS_PIN(0) FPS_PIN(1) FPS_PIN(2) FPS_PIN(3)
  FPS_PIN(4) FPS_PIN(5) FPS_PIN(6) FPS_PIN(7)
  FPS_PIN(8) FPS_PIN(9) FPS_PIN(10) FPS_PIN(11)
  FPS_PIN(12) FPS_PIN(13) FPS_PIN(14) FPS_PIN(15)
  float lx = p[0], ly = p[1], lz = p[2];
  if (tid == 0) {
    samp[b * MPER] = 0;
    out[NEWPOS_OFF + (b * MPER) * 3 + 0] = lx;
    out[NEWPOS_OFF + (b * MPER) * 3 + 1] = ly;
    out[NEWPOS_OFF + (b * MPER) * 3 + 2] = lz;
  }
  __syncthreads();
  for (int s = 1; s < MPER; ++s) {
    // ---- phase A: max distance (float, >= 0) ----
    float m = 0.0f;
    FPS_DIST(0) FPS_DIST(1) FPS_DIST(2) FPS_DIST(3)
    FPS_DIST(4) FPS_DIST(5) FPS_DIST(6) FPS_DIST(7)
    FPS_DIST(8) FPS_DIST(9) FPS_DIST(10) FPS_DIST(11)
    FPS_DIST(12) FPS_DIST(13) FPS_DIST(14) FPS_DIST(15)
    DPP_FMAX(m, 0x111)  // row_shr:1
    DPP_FMAX(m, 0x112)  // row_shr:2
    DPP_FMAX(m, 0x114)  // row_shr:4
    DPP_FMAX(m, 0x118)  // row_shr:8
    DPP_FMAX(m, 0x142)  // row_bcast:15
    DPP_FMAX(m, 0x143)  // row_bcast:31 -> lane 63 has wave max
    if ((tid & 63) == 63) slotD[wv] = __float_as_uint(m);
    __syncthreads();
    const uint4* spD = (const uint4*)slotD;  // broadcast reads
    uint4 a0 = spD[0], a1 = spD[1];
    unsigned int r0 = UMAXU(UMAXU(a0.x, a0.y), UMAXU(a0.z, a0.w));
    unsigned int r1 = UMAXU(UMAXU(a1.x, a1.y), UMAXU(a1.z, a1.w));
    const float D = __uint_as_float(UMAXU(r0, r1));
    // ---- phase B: min index with nd == D ----
    unsigned int ci = 0xFFFFFFFFu;
    FPS_MATCH(15) FPS_MATCH(14) FPS_MATCH(13) FPS_MATCH(12)
    FPS_MATCH(11) FPS_MATCH(10) FPS_MATCH(9) FPS_MATCH(8)
    FPS_MATCH(7) FPS_MATCH(6) FPS_MATCH(5) FPS_MATCH(4)
    FPS_MATCH(3) FPS_MATCH(2) FPS_MATCH(1) FPS_MATCH(0)  // descending: i=0 wins
    DPP_UMIN(ci, 0x111)
    DPP_UMIN(ci, 0x112)
    DPP_UMIN(ci, 0x114)
    DPP_UMIN(ci, 0x118)
    DPP_UMIN(ci, 0x142)
    DPP_UMIN(ci, 0x143)
    if ((tid & 63) == 63) slotI[wv] = ci;
    __syncthreads();
    const uint4* spI = (const uint4*)slotI;  // broadcast reads
    uint4 b0 = spI[0], b1 = spI[1];
    unsigned int i0 = UMINU(UMINU(b0.x, b0.y), UMINU(b0.z, b0.w));
    unsigned int i1 = UMINU(UMINU(b1.x, b1.y), UMINU(b1.z, b1.w));
    const int widx = (int)UMINU(i0, i1);
    // winner xyz: same-address broadcast LDS reads
    float2 wxy = lpxy[widx];
    float wz = lpz[widx];
    lx = wxy.x; ly = wxy.y; lz = wz;
    if (tid == 0) {
      samp[b * MPER + s] = widx;
      out[NEWPOS_OFF + (b * MPER + s) * 3 + 0] = lx;
      out[NEWPOS_OFF + (b * MPER + s) * 3 + 1] = ly;
      out[NEWPOS_OFF + (b * MPER + s) * 3 + 2] = lz;
    }
    // slotD rewrite (next step) is ordered after this step's barrier #2;
    // slotI rewrite after next step's barrier #1 -> no read/write races.
  }
}

// ---------------- kNN: DPP u64 wave-min, single barrier/round, no atomics ----------------
// Same semantics as the r5-verified kernel: extract 16 smallest (d2, n)
// keys (monotone-float<<32 | n, tie -> lowest n); owner removes + rescans.
// Changes: 12-bpermute u64 butterfly -> 6 DPP levels on split halves (pure
// VALU); LDS atomicMin + 2 barriers -> distinct per-wave slots, parity
// double-buffered, ONE barrier (round r+2's write follows barrier r+1 >
// round-r reads); gather-max folded into the rounds (winner n is
// block-uniform -> coalesced h-row load per round, hidden by next round).
#define DPP_KMIN64(lo, hi, CTRL)                                                \
  {                                                                             \
    unsigned int a_ = (unsigned int)__builtin_amdgcn_update_dpp(                \
        (int)(lo), (int)(lo), (CTRL), 0xf, 0xf, false);                         \
    unsigned int b_ = (unsigned int)__builtin_amdgcn_update_dpp(                \
        (int)(hi), (int)(hi), (CTRL), 0xf, 0xf, false);                         \
    unsigned long long nk_ = ((unsigned long long)b_ << 32) | a_;               \
    unsigned long long ok_ = ((unsigned long long)(hi) << 32) | (lo);           \
    bool t_ = nk_ < ok_;                                                        \
    lo = t_ ? a_ : (lo); hi = t_ ? b_ : (hi);                                   \
  }

__global__ __launch_bounds__(256) void knn_kernel(const float* __restrict__ pos,
                                                  const float* __restrict__ sqp,
                                                  const int* __restrict__ samp,
                                                  const float* __restrict__ h,
                                                  float* __restrict__ out) {
  const int q = blockIdx.x;
  const int b = q >> 12;
  const int tid = threadIdx.x;
  const int wv = tid >> 6;  // wave 0..3
  const int gbase = b * NPER;
  __shared__ float dist[NPER];  // 32 KB
  __shared__ __align__(16) unsigned long long ckey[2][4];
  const int sidx = samp[q];
  const float qx = pos[(gbase + sidx) * 3 + 0];
  const float qy = pos[(gbase + sidx) * 3 + 1];
  const float qz = pos[(gbase + sidx) * 3 + 2];
  const float sqq = sqp[gbase + sidx];
  unsigned long long lkey = ~0ull;
  for (int i = 0; i < 32; ++i) {
    int n = tid + i * 256;
    int g = gbase + n;
    // Eigen gebp: fma(q2,p2, fma(q1,p1, rn(q0*p0)))
    float dot = fmaf(qz, pos[g * 3 + 2],
                     fmaf(qy, pos[g * 3 + 1], __fmul_rn(qx, pos[g * 3 + 0])));
    // (sq_q + sq_p) - 2*dot, each op rounded
    float d2 = __fsub_rn(__fadd_rn(sqq, sqp[g]), __fmul_rn(2.0f, dot));
    dist[n] = d2;
    unsigned int ub = __float_as_uint(d2);
    ub = (ub & 0x80000000u) ? ~ub : (ub | 0x80000000u);  // monotone float->uint
    unsigned long long key = ((unsigned long long)ub << 32) | (unsigned int)n;
    lkey = (key < lkey) ? key : lkey;
  }
  __syncthreads();
  float mx = -INFINITY;
  for (int r = 0; r < 16; ++r) {
    const int pr = r & 1;
    unsigned int klo = (unsigned int)lkey;
    unsigned int khi = (unsigned int)(lkey >> 32);
    DPP_KMIN64(klo, khi, 0x111)  // row_shr:1
    DPP_KMIN64(klo, khi, 0x112)  // row_shr:2
    DPP_KMIN64(klo, khi, 0x114)  // row_shr:4
    DPP_KMIN64(klo, khi, 0x118)  // row_shr:8
    DPP_KMIN64(klo, khi, 0x142)  // row_bcast:15
    DPP_KMIN64(klo, khi, 0x143)  // row_bcast:31 -> lane 63 has wave min
    if ((tid & 63) == 63)
      ckey[pr][wv] = ((unsigned long long)khi << 32) | klo;
    __syncthreads();
    const ulonglong2* cp = (const ulonglong2*)ckey[pr];  // broadcast reads
    ulonglong2 c0 = cp[0], c1 = cp[1];
    unsigned long long k0 = (c0.x < c0.y) ? c0.x : c0.y;
    unsigned long long k1 = (c1.x < c1.y) ? c1.x : c1.y;
    k0 = (k1 < k0) ? k1 : k0;
    const int n = (int)(unsigned int)(k0 & 0xFFFFFFFFull);
    // fold gather-max: winner row load is block-uniform & coalesced
    if (tid < COUT) mx = fmaxf(mx, h[(gbase + n) * 128 + tid]);
    if (tid == (n & 255)) {  // owner removes it and refreshes its local min
      dist[n] = INFINITY;
      lkey = ~0ull;
      for (int i = 0; i < 32; ++i) {
        int nn = tid + i * 256;
        unsigned int ub = __float_as_uint(dist[nn]);
        ub = (ub & 0x80000000u) ? ~ub : (ub | 0x80000000u);
        unsigned long long kk = ((unsigned long long)ub << 32) | (unsigned int)nn;
        lkey = (kk < lkey) ? kk : lkey;
      }
    }
    // single barrier per round: round r+2's rewrite of ckey[pr] happens
    // after barrier r+1, which follows all round-r reads (parity buffer).
  }
  if (tid < COUT) out[q * 128 + tid] = mx;
}

extern "C" void kernel_launch(void* const* d_in, const int* in_sizes, int n_in,
                              void* d_out, int out_size, void* d_ws, size_t ws_size,
                              hipStream_t stream) {
  (void)in_sizes; (void)n_in; (void)out_size; (void)ws_size;
  const float* x     = (const float*)d_in[0];
  const float* pos   = (const float*)d_in[1];
  const float* W     = (const float*)d_in[3];
  const float* bias  = (const float*)d_in[4];
  const float* gamma = (const float*)d_in[5];
  const float* beta  = (const float*)d_in[6];
  float* out = (float*)d_out;
  char* ws = (char*)d_ws;
  float* h     = (float*)(ws + WS_H);
  float* sqp   = (float*)(ws + WS_SQP);
  int*   samp  = (int*)(ws + WS_SAMP);
  float* part  = (float*)(ws + WS_PART);
  float* part2 = (float*)(ws + WS_PART2);
  float* stat  = (float*)(ws + WS_STAT);

  misc_kernel<<<dim3(32), dim3(1024), 0, stream>>>(pos, sqp, out);
  matmul_kernel<<<dim3(2048), dim3(256), 0, stream>>>(x, W, bias, h);
  stats_kernel<<<dim3(64), dim3(256), 0, stream>>>(h, part, part2);
  finalize_kernel<<<dim3(1), dim3(128), 0, stream>>>(part, part2, stat);
  bngelu_kernel<<<dim3(2048), dim3(256), 0, stream>>>(h, stat, gamma, beta);
  fps_kernel<<<dim3(NB), dim3(512), 0, stream>>>(pos, samp, out);
  knn_kernel<<<dim3(MTOT), dim3(256), 0, stream>>>(pos, sqp, samp, h, out);
}